// Round 10
// baseline (36.978 us; speedup 1.0000x reference)
//
#include <hip/hip_runtime.h>

// out[z,k] = sum_{i,j} C[k,i,j] * f1[z,i] * f2[z,j]
// Z=4096, K=3600, I=J=60, fp32.
//
// Round 10: store-pattern redesign. Block = 4 consecutive z x ALL 3600 k.
// Results go to an LDS tile out_lds[4][3648]; a final sweep writes ONE
// contiguous 57.6KB slab per block (fillBuffer-style sequential stores,
// which measure 6.7 TB/s on this chip vs ~2.3 TB/s for our old scattered
// 256-512B chunks). 57 k-waves partitioned at compile time into 4 equal-cost
// job lists (92/90/92/90), grouped by padded (D1,D2) shape -> fully static
// templates, zero decode. Pack kernel bakes SoA c-table (181KB, L2-resident,
// coalesced) + ushort (i0,j0) table.

#define NF    60
#define KTOT  3600
#define BLOCK 256
#define OLS   3648                 // out_lds row stride (>= 3647+1, %32==0)
#define PK_UNITS 177               // total NC4 prefix sum over 57 k-waves
#define PIJ_OFF  (PK_UNITS * 64 * 16)   // 181248 B

typedef float f32x4 __attribute__((ext_vector_type(4)));

struct Seg { short kstart, mul2, dl, d1, d2, ioff, joff, pad; };

__constant__ Seg c_segs[19] = {
  {   0,16,1,1,1, 0, 0,0}, { 256, 8,3,1,3, 0,16,0}, { 640, 4,5,1,5, 0,40,0},
  { 960,16,3,3,1,16, 0,0}, {1344, 8,1,3,3,16,16,0}, {1408, 8,3,3,3,16,16,0},
  {1600, 8,5,3,3,16,16,0}, {1920, 4,3,3,5,16,40,0}, {2016, 4,5,3,5,16,40,0},
  {2176, 4,7,3,5,16,40,0}, {2400,16,5,5,1,40, 0,0}, {2720, 8,3,5,3,40,16,0},
  {2816, 8,5,5,3,40,16,0}, {2976, 8,7,5,3,40,16,0}, {3200, 4,1,5,5,40,40,0},
  {3216, 4,3,5,5,40,40,0}, {3264, 4,5,5,5,40,40,0}, {3344, 4,7,5,5,40,40,0},
  {3456, 4,9,5,5,40,40,0}
};

// Per-k-wave (kw = k>>6, 57 waves) PADDED shapes (max over covered segments;
// waves 37/42/46/50/52 cross segment boundaries).
__constant__ unsigned char c_wd1[57] = {
  1,1,1,1, 1,1,1,1,1,1, 1,1,1,1,1, 3,3,3,3,3,3, 3,3,3,3,3,3,3,3,3,
  3,3,3,3,3,3,3, 5, 5,5,5,5, 5, 5,5,5,5,5,5,5, 5,5,5,5,5,5,5 };
__constant__ unsigned char c_wd2[57] = {
  1,1,1,1, 3,3,3,3,3,3, 5,5,5,5,5, 1,1,1,1,1,1, 3,3,3,3,3,3,3,3,3,
  5,5,5,5,5,5,5, 5, 1,1,1,1, 3, 3,3,3,3,3,3,3, 5,5,5,5,5,5,5 };
// Prefix sum of NC4 = ceil(D1p*D2p/4) per k-wave (units of 64 f32x4).
__constant__ short c_woff[57] = {
  0,1,2,3, 4,5,6,7,8,9, 10,12,14,16,18, 20,21,22,23,24,25,
  26,29,32,35,38,41,44,47,50, 53,57,61,65,69,73,77, 81, 88,90,92,94, 96,
  100,104,108,112,116,120,124, 128,135,142,149,156,163,170 };

// Compile-time balanced job lists (cost = D1p+D2p; rows sum 92/90/92/90).
__constant__ unsigned char J0a[8] = {37,50,51,52,53,54,55,56};  // (5,5)
__constant__ unsigned char J0b[1] = {30};                       // (3,5)
__constant__ unsigned char J0c[1] = {4};                        // (1,3)
__constant__ unsigned char J1a[6] = {31,32,33,34,35,36};        // (3,5)
__constant__ unsigned char J1b[5] = {42,43,44,45,46};           // (5,3)
__constant__ unsigned char J1c[1] = {0};                        // (1,1)
__constant__ unsigned char J2a[3] = {47,48,49};                 // (5,3)
__constant__ unsigned char J2b[5] = {10,11,12,13,14};           // (1,5)
__constant__ unsigned char J2c[6] = {21,22,23,24,25,26};        // (3,3)
__constant__ unsigned char J2d[1] = {1};                        // (1,1)
__constant__ unsigned char J3a[3] = {27,28,29};                 // (3,3)
__constant__ unsigned char J3b[4] = {38,39,40,41};              // (5,1)
__constant__ unsigned char J3c[5] = {5,6,7,8,9};                // (1,3)
__constant__ unsigned char J3d[6] = {15,16,17,18,19,20};        // (3,1)
__constant__ unsigned char J3e[2] = {2,3};                      // (1,1)

__device__ __forceinline__ void decode_k(int kc, Seg& sg, int& i0, int& j0) {
  int s = 0;
  s += (kc >=  256); s += (kc >=  640); s += (kc >=  960); s += (kc >= 1344);
  s += (kc >= 1408); s += (kc >= 1600); s += (kc >= 1920); s += (kc >= 2016);
  s += (kc >= 2176); s += (kc >= 2400); s += (kc >= 2720); s += (kc >= 2816);
  s += (kc >= 2976); s += (kc >= 3200); s += (kc >= 3216); s += (kc >= 3264);
  s += (kc >= 3344); s += (kc >= 3456);
  sg = c_segs[s];
  const int local = kc - sg.kstart;
  const int uv = local / sg.dl;
  const int u  = uv / sg.mul2;
  const int v  = uv - u * sg.mul2;
  i0 = sg.ioff + u * sg.d1;
  j0 = sg.joff + v * sg.d2;
}

// ---------- pack: 8 threads per k (rows 0-4 + meta slot 5) ----------
__global__ __launch_bounds__(BLOCK) void pack_kernel(
    const float* __restrict__ M, float* __restrict__ pk,
    unsigned short* __restrict__ pij)
{
  const int tid = blockIdx.x * BLOCK + (int)threadIdx.x;
  if (tid >= 3648 * 8) return;
  const int k = tid >> 3, slot = tid & 7;
  if (slot >= 6) return;
  const int kw = k >> 6, lane = k & 63;
  const int D1p = c_wd1[kw], D2p = c_wd2[kw];
  const int nc4 = (D1p * D2p + 3) >> 2;
  const int wo  = (int)c_woff[kw];
  const bool kvalid = k < KTOT;
  Seg sg{}; int i0 = 0, j0 = 0;
  if (kvalid) decode_k(k, sg, i0, j0);
  if (slot == 5) {
    pij[k] = kvalid ? (unsigned short)(i0 | (j0 << 8)) : (unsigned short)0;
    for (int p = D1p * D2p; p < nc4 * 4; ++p)
      pk[((size_t)(wo + (p >> 2)) * 64 + lane) * 4 + (p & 3)] = 0.f;
    return;
  }
  const int ii = slot;
  if (ii >= D1p) return;
  for (int jj = 0; jj < D2p; ++jj) {
    float v = 0.f;
    if (kvalid && ii < sg.d1 && jj < sg.d2)
      v = M[(size_t)k * (NF * NF) + (size_t)(i0 + ii) * NF + (j0 + jj)];
    const int p = ii * D2p + jj;
    pk[((size_t)(wo + (p >> 2)) * 64 + lane) * 4 + (p & 3)] = v;
  }
}

// ---------- compute ----------
template<int D1, int D2>
__device__ void run_group(const unsigned char* __restrict__ kws, int n,
    const float* __restrict__ pk, const unsigned short* __restrict__ pij,
    int lane,
    const float (&f1s)[NF][4], const float (&f2s)[NF][4],
    float* __restrict__ out_lds)
{
  constexpr int NC4 = (D1 * D2 + 3) / 4;
#pragma unroll 2
  for (int jj = 0; jj < n; ++jj) {
    const int kw = (int)kws[jj];
    const int k  = kw * 64 + lane;
    const int wo = (int)c_woff[kw];
    const unsigned short w = pij[k];
    const int i0 = w & 255, j0 = w >> 8;
    float c[NC4 * 4];
#pragma unroll
    for (int p4 = 0; p4 < NC4; ++p4) {
      const f32x4 v = *(const f32x4*)(pk + ((size_t)(wo + p4) * 64 + lane) * 4);
      c[4*p4+0] = v[0]; c[4*p4+1] = v[1]; c[4*p4+2] = v[2]; c[4*p4+3] = v[3];
    }
    f32x4 A[D1], B[D2];
#pragma unroll
    for (int t = 0; t < D1; ++t) A[t] = *(const f32x4*)&f1s[i0 + t][0];
#pragma unroll
    for (int t = 0; t < D2; ++t) B[t] = *(const f32x4*)&f2s[j0 + t][0];
#pragma unroll
    for (int q = 0; q < 4; ++q) {
      float acc = 0.f;
      if constexpr (D1 <= D2) {
#pragma unroll
        for (int ii = 0; ii < D1; ++ii) {
          float t0 = c[ii * D2] * B[0][q];
#pragma unroll
          for (int j2 = 1; j2 < D2; ++j2) t0 = fmaf(c[ii * D2 + j2], B[j2][q], t0);
          acc = fmaf(t0, A[ii][q], acc);
        }
      } else {
#pragma unroll
        for (int j2 = 0; j2 < D2; ++j2) {
          float t0 = c[j2] * A[0][q];
#pragma unroll
          for (int ii = 1; ii < D1; ++ii) t0 = fmaf(c[ii * D2 + j2], A[ii][q], t0);
          acc = fmaf(t0, B[j2][q], acc);
        }
      }
      out_lds[q * OLS + k] = acc;
    }
  }
}

__global__ __launch_bounds__(BLOCK) void tp_kernel(
    const float* __restrict__ f1, const float* __restrict__ f2,
    const float* __restrict__ pk, const unsigned short* __restrict__ pij,
    float* __restrict__ out)
{
  __shared__ __align__(16) float f1s[NF][4];
  __shared__ __align__(16) float f2s[NF][4];
  __shared__ __align__(16) float out_lds[4 * OLS];
  const int z0  = (int)blockIdx.x * 4;
  const int tid = (int)threadIdx.x;
  const int wv  = tid >> 6, lane = tid & 63;

  // Stage the 4x60 feature tiles, feature-major (f[feat][z]).
  if (tid < 60) {
    const f32x4 v = *(const f32x4*)(f1 + (size_t)z0 * NF + 4 * tid);
    const int g = 4 * tid, z = g / NF, f0 = g % NF;
    f1s[f0+0][z] = v[0]; f1s[f0+1][z] = v[1];
    f1s[f0+2][z] = v[2]; f1s[f0+3][z] = v[3];
  } else if (tid >= 64 && tid < 124) {
    const int t = tid - 64;
    const f32x4 v = *(const f32x4*)(f2 + (size_t)z0 * NF + 4 * t);
    const int g = 4 * t, z = g / NF, f0 = g % NF;
    f2s[f0+0][z] = v[0]; f2s[f0+1][z] = v[1];
    f2s[f0+2][z] = v[2]; f2s[f0+3][z] = v[3];
  }
  __syncthreads();

  // Per-wave compile-time job schedule (cost 92/90/92/90).
  if (wv == 0) {
    run_group<5,5>(J0a, 8, pk, pij, lane, f1s, f2s, out_lds);
    run_group<3,5>(J0b, 1, pk, pij, lane, f1s, f2s, out_lds);
    run_group<1,3>(J0c, 1, pk, pij, lane, f1s, f2s, out_lds);
  } else if (wv == 1) {
    run_group<3,5>(J1a, 6, pk, pij, lane, f1s, f2s, out_lds);
    run_group<5,3>(J1b, 5, pk, pij, lane, f1s, f2s, out_lds);
    run_group<1,1>(J1c, 1, pk, pij, lane, f1s, f2s, out_lds);
  } else if (wv == 2) {
    run_group<5,3>(J2a, 3, pk, pij, lane, f1s, f2s, out_lds);
    run_group<1,5>(J2b, 5, pk, pij, lane, f1s, f2s, out_lds);
    run_group<3,3>(J2c, 6, pk, pij, lane, f1s, f2s, out_lds);
    run_group<1,1>(J2d, 1, pk, pij, lane, f1s, f2s, out_lds);
  } else {
    run_group<3,3>(J3a, 3, pk, pij, lane, f1s, f2s, out_lds);
    run_group<5,1>(J3b, 4, pk, pij, lane, f1s, f2s, out_lds);
    run_group<1,3>(J3c, 5, pk, pij, lane, f1s, f2s, out_lds);
    run_group<3,1>(J3d, 6, pk, pij, lane, f1s, f2s, out_lds);
    run_group<1,1>(J3e, 2, pk, pij, lane, f1s, f2s, out_lds);
  }
  __syncthreads();

  // Sweep: one contiguous 57.6KB slab per block, fully coalesced f32x4.
  float* ob = out + (size_t)z0 * KTOT;
#pragma unroll
  for (int z = 0; z < 4; ++z)
    for (int t = tid; t < KTOT / 4; t += BLOCK)
      *(f32x4*)(ob + (size_t)z * KTOT + 4 * t) =
          *(const f32x4*)&out_lds[z * OLS + 4 * t];
}

extern "C" void kernel_launch(void* const* d_in, const int* in_sizes, int n_in,
                              void* d_out, int out_size, void* d_ws, size_t ws_size,
                              hipStream_t stream) {
  const float* f1 = (const float*)d_in[0];
  const float* f2 = (const float*)d_in[1];
  const float* M  = (const float*)d_in[2];
  float* out = (float*)d_out;
  float* pk  = (float*)d_ws;                                   // 181,248 B
  unsigned short* pij = (unsigned short*)((char*)d_ws + PIJ_OFF); // 7,296 B

  pack_kernel<<<dim3((3648 * 8) / BLOCK), dim3(BLOCK), 0, stream>>>(M, pk, pij);

  const int Z = in_sizes[0] / NF;          // 4096
  tp_kernel<<<dim3(Z / 4), dim3(BLOCK), 0, stream>>>(f1, f2, pk, pij, out);
}

// Round 11
// 27.348 us; speedup vs baseline: 1.3521x; 1.3521x over previous
//
#include <hip/hip_runtime.h>

// out[z,k] = sum_{i,j} C[k,i,j] * f1[z,i] * f2[z,j]
// Z=4096, K=3600, I=J=60, fp32.
//
// Round 11: R4 structure with (1) ZT=32 (16.6KB LDS), (2) launch_bounds
// (256,4) -> 4 waves/SIMD (R4's ",3" capped occupancy at 3; R9 showed
// VGPR-bloat halving occupancy cost 4us), (3) PLAIN stores (nontemporal
// hints bypass L2 write-combining -> partial DRAM bursts; fillBuffer's
// plain stores hit 6.7 TB/s). Store-pattern itself proven irrelevant (R10
// slab test). Balanced kwmap / branchless decode / pre-barrier c-gather /
// ping-pong z-loop unchanged from R4.

#define ZT    32
#define ZPAD  36     // row stride (floats): 16B-aligned b128, spread banks
#define NF    60
#define KTOT  3600
#define BLOCK 256
#define NLD   ((ZT * NF) / 4)   // 480 f32x4 per feature tile

typedef float f32x4 __attribute__((ext_vector_type(4)));

struct Seg { short kstart, mul2, dl, d1, d2, ioff, joff, pad; };

__constant__ Seg c_segs[19] = {
  {   0,16,1,1,1, 0, 0,0}, { 256, 8,3,1,3, 0,16,0}, { 640, 4,5,1,5, 0,40,0},
  { 960,16,3,3,1,16, 0,0}, {1344, 8,1,3,3,16,16,0}, {1408, 8,3,3,3,16,16,0},
  {1600, 8,5,3,3,16,16,0}, {1920, 4,3,3,5,16,40,0}, {2016, 4,5,3,5,16,40,0},
  {2176, 4,7,3,5,16,40,0}, {2400,16,5,5,1,40, 0,0}, {2720, 8,3,5,3,40,16,0},
  {2816, 8,5,5,3,40,16,0}, {2976, 8,7,5,3,40,16,0}, {3200, 4,1,5,5,40,40,0},
  {3216, 4,3,5,5,40,40,0}, {3264, 4,5,5,5,40,40,0}, {3344, 4,7,5,5,40,40,0},
  {3456, 4,9,5,5,40,40,0}
};

// Balanced (block, wave) -> k-wave map; every row's cost sums to 24. -1=dummy.
__constant__ short c_kwmap[15][4] = {
  {50,30, 4, 0}, {51,31, 5, 1}, {52,32, 6, 2}, {53,33, 7, 3},
  {54,34,10,-1}, {55,35,11,-1}, {56,36,12,-1},
  {37,43, 8,15}, {44,45, 9,16}, {46,47,17,18}, {48,49,19,20},
  {13,14,21,22}, {23,24,25,26}, {27,28,29,38}, {39,40,41,42}
};

__device__ __forceinline__ void decode_k(int kc, Seg& sg, int& i0, int& j0) {
  int s = 0;
  s += (kc >=  256); s += (kc >=  640); s += (kc >=  960); s += (kc >= 1344);
  s += (kc >= 1408); s += (kc >= 1600); s += (kc >= 1920); s += (kc >= 2016);
  s += (kc >= 2176); s += (kc >= 2400); s += (kc >= 2720); s += (kc >= 2816);
  s += (kc >= 2976); s += (kc >= 3200); s += (kc >= 3216); s += (kc >= 3264);
  s += (kc >= 3344); s += (kc >= 3456);
  sg = c_segs[s];
  const int local = kc - sg.kstart;
  const int uv = local / sg.dl;
  const int u  = uv / sg.mul2;
  const int v  = uv - u * sg.mul2;
  i0 = sg.ioff + u * sg.d1;
  j0 = sg.joff + v * sg.d2;
}

template<int D1, int D2>
__device__ __forceinline__ void load_c(float (&c)[25],
    const float* __restrict__ Crow, int i0, int j0)
{
#pragma unroll
  for (int ii = 0; ii < D1; ++ii)
#pragma unroll
    for (int jj = 0; jj < D2; ++jj)
      c[ii * D2 + jj] = Crow[(i0 + ii) * NF + (j0 + jj)];
}

template<int D1, int D2>
__device__ __forceinline__ void ld_ab(f32x4 (&a)[D1], f32x4 (&b)[D2],
    const float (&f1s)[NF][ZPAD], const float (&f2s)[NF][ZPAD],
    int i0, int j0, int zz)
{
#pragma unroll
  for (int ii = 0; ii < D1; ++ii) a[ii] = *(const f32x4*)&f1s[i0 + ii][zz];
#pragma unroll
  for (int jj = 0; jj < D2; ++jj) b[jj] = *(const f32x4*)&f2s[j0 + jj][zz];
}

template<int D1, int D2>
__device__ __forceinline__ void comp_st(const float (&c)[25],
    const f32x4 (&a)[D1], const f32x4 (&b)[D2], float* __restrict__ opz)
{
#pragma unroll
  for (int q = 0; q < 4; ++q) {
    float acc;
    if constexpr (D1 <= D2) {
      acc = 0.f;
#pragma unroll
      for (int ii = 0; ii < D1; ++ii) {
        float t = c[ii * D2] * b[0][q];
#pragma unroll
        for (int jj = 1; jj < D2; ++jj) t = fmaf(c[ii * D2 + jj], b[jj][q], t);
        acc = fmaf(t, a[ii][q], acc);
      }
    } else {
      acc = 0.f;
#pragma unroll
      for (int jj = 0; jj < D2; ++jj) {
        float t = c[jj] * a[0][q];
#pragma unroll
        for (int ii = 1; ii < D1; ++ii) t = fmaf(c[ii * D2 + jj], a[ii][q], t);
        acc = fmaf(t, b[jj][q], acc);
      }
    }
    opz[(size_t)q * KTOT] = acc;   // plain store (NO nontemporal)
  }
}

// 2-deep ping-pong pipeline with statically named register sets.
template<int D1, int D2>
__device__ void tp_body(const float (&c)[25], int i0, int j0,
    const float (&f1s)[NF][ZPAD], const float (&f2s)[NF][ZPAD],
    float* __restrict__ op)     // = out + z0*KTOT + k
{
  f32x4 aA[D1], bA[D2], aB[D1], bB[D2];
  ld_ab<D1,D2>(aA, bA, f1s, f2s, i0, j0, 0);
#pragma unroll 1
  for (int zz = 0; zz < ZT; zz += 8) {
    ld_ab<D1,D2>(aB, bB, f1s, f2s, i0, j0, zz + 4);
    comp_st<D1,D2>(c, aA, bA, op + (size_t)zz * KTOT);
    if (zz + 8 < ZT) ld_ab<D1,D2>(aA, bA, f1s, f2s, i0, j0, zz + 8);
    comp_st<D1,D2>(c, aB, bB, op + (size_t)(zz + 4) * KTOT);
  }
}

__global__ __launch_bounds__(BLOCK, 4) void tp_kernel(
    const float* __restrict__ f1, const float* __restrict__ f2,
    const float* __restrict__ M, float* __restrict__ out)
{
  __shared__ __align__(16) float f1s[NF][ZPAD];
  __shared__ __align__(16) float f2s[NF][ZPAD];
  const int z0  = blockIdx.y * ZT;
  const int tid = (int)threadIdx.x;

  // (1) Issue feature-tile staging loads (coalesced f32x4) into registers.
  const float* f1p = f1 + (size_t)z0 * NF;
  const float* f2p = f2 + (size_t)z0 * NF;
  f32x4 s1[2], s2[2];
#pragma unroll
  for (int r = 0; r < 2; ++r) {
    const int t = tid + r * BLOCK;
    if (t < NLD) {
      s1[r] = *(const f32x4*)(f1p + 4 * t);
      s2[r] = *(const f32x4*)(f2p + 4 * t);
    }
  }

  // (2) Balanced k-wave lookup + branchless segment decode.
  const int wv   = tid >> 6;
  const int lane = tid & 63;
  const int kw   = (int)c_kwmap[blockIdx.x][(wv + (int)blockIdx.y) & 3];
  const int k    = (kw << 6) + lane;
  const bool active = (kw >= 0) && (k < KTOT);
  const int kc = active ? k : 0;
  Seg sg; int i0, j0;
  decode_k(kc, sg, i0, j0);
  const float* Crow = M + (size_t)kc * (NF * NF);

  // (3) Issue c[] loads NOW — latency rides through ds_write + barrier.
  float c[25];
  const int d1 = sg.d1, d2 = sg.d2;
  if (d1 == 1) {
    if (d2 == 1)      load_c<1,1>(c, Crow, i0, j0);
    else if (d2 == 3) load_c<1,3>(c, Crow, i0, j0);
    else              load_c<1,5>(c, Crow, i0, j0);
  } else if (d1 == 3) {
    if (d2 == 1)      load_c<3,1>(c, Crow, i0, j0);
    else if (d2 == 3) load_c<3,3>(c, Crow, i0, j0);
    else              load_c<3,5>(c, Crow, i0, j0);
  } else {
    if (d2 == 1)      load_c<5,1>(c, Crow, i0, j0);
    else if (d2 == 3) load_c<5,3>(c, Crow, i0, j0);
    else              load_c<5,5>(c, Crow, i0, j0);
  }

  // (4) Transposed LDS write (feature-major): f1s[f][z].
#pragma unroll
  for (int r = 0; r < 2; ++r) {
    const int t = tid + r * BLOCK;
    if (t < NLD) {
      const int g = 4 * t, zz = g / NF, f0 = g % NF;
      f1s[f0+0][zz] = s1[r][0]; f1s[f0+1][zz] = s1[r][1];
      f1s[f0+2][zz] = s1[r][2]; f1s[f0+3][zz] = s1[r][3];
      f2s[f0+0][zz] = s2[r][0]; f2s[f0+1][zz] = s2[r][1];
      f2s[f0+2][zz] = s2[r][2]; f2s[f0+3][zz] = s2[r][3];
    }
  }
  __syncthreads();
  if (!active) return;

  float* op = out + (size_t)z0 * KTOT + k;

  if (d1 == 1) {
    if (d2 == 1)      tp_body<1,1>(c, i0, j0, f1s, f2s, op);
    else if (d2 == 3) tp_body<1,3>(c, i0, j0, f1s, f2s, op);
    else              tp_body<1,5>(c, i0, j0, f1s, f2s, op);
  } else if (d1 == 3) {
    if (d2 == 1)      tp_body<3,1>(c, i0, j0, f1s, f2s, op);
    else if (d2 == 3) tp_body<3,3>(c, i0, j0, f1s, f2s, op);
    else              tp_body<3,5>(c, i0, j0, f1s, f2s, op);
  } else {
    if (d2 == 1)      tp_body<5,1>(c, i0, j0, f1s, f2s, op);
    else if (d2 == 3) tp_body<5,3>(c, i0, j0, f1s, f2s, op);
    else              tp_body<5,5>(c, i0, j0, f1s, f2s, op);
  }
}

extern "C" void kernel_launch(void* const* d_in, const int* in_sizes, int n_in,
                              void* d_out, int out_size, void* d_ws, size_t ws_size,
                              hipStream_t stream) {
  const float* f1 = (const float*)d_in[0];
  const float* f2 = (const float*)d_in[1];
  const float* M  = (const float*)d_in[2];
  float* out = (float*)d_out;

  const int Z = in_sizes[0] / NF;          // 4096
  dim3 grid(15, Z / ZT);                   // 15 x 128 = 1920 blocks
  tp_kernel<<<grid, dim3(BLOCK), 0, stream>>>(f1, f2, M, out);
}

// Round 12
// 27.248 us; speedup vs baseline: 1.3571x; 1.0037x over previous
//
#include <hip/hip_runtime.h>

// out[z,k] = sum_{i,j} C[k,i,j] * f1[z,i] * f2[z,j]
// Z=4096, K=3600, I=J=60, fp32.
//
// Round 12: definitive slab-store test with non-broken compute.
// Block = 4 z x ALL 3600 k, 512 threads (8 waves). Results staged in
// out_lds[4][3648]; final sweep writes ONE contiguous 57.6KB slab per
// block (fillBuffer pattern, 6.7 TB/s proven). R10's compute diseases
// fixed: 8 waves -> ~7 jobs/wave (was 45 at 2 waves/SIMD -> c-latency
// bound), 2 blocks/CU resident (phase overlap), coalesced pk c-table
// (R10's pack kernel reused verbatim), hand-balanced per-wave static
// job schedule (44-48 cost units), all shapes compile-time.

#define NF    60
#define KTOT  3600
#define OLS   3648
#define PK_UNITS 177
#define PIJ_OFF  (PK_UNITS * 64 * 16)   // 181248 B

typedef float f32x4 __attribute__((ext_vector_type(4)));

struct Seg { short kstart, mul2, dl, d1, d2, ioff, joff, pad; };

__constant__ Seg c_segs[19] = {
  {   0,16,1,1,1, 0, 0,0}, { 256, 8,3,1,3, 0,16,0}, { 640, 4,5,1,5, 0,40,0},
  { 960,16,3,3,1,16, 0,0}, {1344, 8,1,3,3,16,16,0}, {1408, 8,3,3,3,16,16,0},
  {1600, 8,5,3,3,16,16,0}, {1920, 4,3,3,5,16,40,0}, {2016, 4,5,3,5,16,40,0},
  {2176, 4,7,3,5,16,40,0}, {2400,16,5,5,1,40, 0,0}, {2720, 8,3,5,3,40,16,0},
  {2816, 8,5,5,3,40,16,0}, {2976, 8,7,5,3,40,16,0}, {3200, 4,1,5,5,40,40,0},
  {3216, 4,3,5,5,40,40,0}, {3264, 4,5,5,5,40,40,0}, {3344, 4,7,5,5,40,40,0},
  {3456, 4,9,5,5,40,40,0}
};

// Per-k-wave (kw = k>>6, 57 waves) PADDED shapes.
__constant__ unsigned char c_wd1[57] = {
  1,1,1,1, 1,1,1,1,1,1, 1,1,1,1,1, 3,3,3,3,3,3, 3,3,3,3,3,3,3,3,3,
  3,3,3,3,3,3,3, 5, 5,5,5,5, 5, 5,5,5,5,5,5,5, 5,5,5,5,5,5,5 };
__constant__ unsigned char c_wd2[57] = {
  1,1,1,1, 3,3,3,3,3,3, 5,5,5,5,5, 1,1,1,1,1,1, 3,3,3,3,3,3,3,3,3,
  5,5,5,5,5,5,5, 5, 1,1,1,1, 3, 3,3,3,3,3,3,3, 5,5,5,5,5,5,5 };
// Prefix sum of NC4 = ceil(D1p*D2p/4) per k-wave.
__constant__ short c_woff[57] = {
  0,1,2,3, 4,5,6,7,8,9, 10,12,14,16,18, 20,21,22,23,24,25,
  26,29,32,35,38,41,44,47,50, 53,57,61,65,69,73,77, 81, 88,90,92,94, 96,
  100,104,108,112,116,120,124, 128,135,142,149,156,163,170 };

__device__ __forceinline__ void decode_k(int kc, Seg& sg, int& i0, int& j0) {
  int s = 0;
  s += (kc >=  256); s += (kc >=  640); s += (kc >=  960); s += (kc >= 1344);
  s += (kc >= 1408); s += (kc >= 1600); s += (kc >= 1920); s += (kc >= 2016);
  s += (kc >= 2176); s += (kc >= 2400); s += (kc >= 2720); s += (kc >= 2816);
  s += (kc >= 2976); s += (kc >= 3200); s += (kc >= 3216); s += (kc >= 3264);
  s += (kc >= 3344); s += (kc >= 3456);
  sg = c_segs[s];
  const int local = kc - sg.kstart;
  const int uv = local / sg.dl;
  const int u  = uv / sg.mul2;
  const int v  = uv - u * sg.mul2;
  i0 = sg.ioff + u * sg.d1;
  j0 = sg.joff + v * sg.d2;
}

// ---------- pack (verbatim from R10, proven correct) ----------
__global__ __launch_bounds__(256) void pack_kernel(
    const float* __restrict__ M, float* __restrict__ pk,
    unsigned short* __restrict__ pij)
{
  const int tid = blockIdx.x * 256 + (int)threadIdx.x;
  if (tid >= 3648 * 8) return;
  const int k = tid >> 3, slot = tid & 7;
  if (slot >= 6) return;
  const int kw = k >> 6, lane = k & 63;
  const int D1p = c_wd1[kw], D2p = c_wd2[kw];
  const int nc4 = (D1p * D2p + 3) >> 2;
  const int wo  = (int)c_woff[kw];
  const bool kvalid = k < KTOT;
  Seg sg{}; int i0 = 0, j0 = 0;
  if (kvalid) decode_k(k, sg, i0, j0);
  if (slot == 5) {
    pij[k] = kvalid ? (unsigned short)(i0 | (j0 << 8)) : (unsigned short)0;
    for (int p = D1p * D2p; p < nc4 * 4; ++p)
      pk[((size_t)(wo + (p >> 2)) * 64 + lane) * 4 + (p & 3)] = 0.f;
    return;
  }
  const int ii = slot;
  if (ii >= D1p) return;
  for (int jj = 0; jj < D2p; ++jj) {
    float v = 0.f;
    if (kvalid && ii < sg.d1 && jj < sg.d2)
      v = M[(size_t)k * (NF * NF) + (size_t)(i0 + ii) * NF + (j0 + jj)];
    const int p = ii * D2p + jj;
    pk[((size_t)(wo + (p >> 2)) * 64 + lane) * 4 + (p & 3)] = v;
  }
}

// ---------- compute ----------
template<int D1, int D2>
__device__ __forceinline__ void run_one(int kw,
    const float* __restrict__ pk, const unsigned short* __restrict__ pij,
    int lane, const float* __restrict__ f1s, const float* __restrict__ f2s,
    float* __restrict__ out_lds)
{
  constexpr int NC4 = (D1 * D2 + 3) / 4;
  const int k  = kw * 64 + lane;
  const int wo = (int)c_woff[kw];
  const unsigned short w = pij[k];
  const int i0 = w & 255, j0 = w >> 8;
  float c[NC4 * 4];
#pragma unroll
  for (int p4 = 0; p4 < NC4; ++p4) {
    const f32x4 v = *(const f32x4*)(pk + ((size_t)(wo + p4) * 64 + lane) * 4);
    c[4*p4+0] = v[0]; c[4*p4+1] = v[1]; c[4*p4+2] = v[2]; c[4*p4+3] = v[3];
  }
  f32x4 A[D1], B[D2];
#pragma unroll
  for (int t = 0; t < D1; ++t) A[t] = *(const f32x4*)&f1s[(i0 + t) * 4];
#pragma unroll
  for (int t = 0; t < D2; ++t) B[t] = *(const f32x4*)&f2s[(j0 + t) * 4];
#pragma unroll
  for (int q = 0; q < 4; ++q) {
    float acc = 0.f;
    if constexpr (D1 <= D2) {
#pragma unroll
      for (int ii = 0; ii < D1; ++ii) {
        float t0 = c[ii * D2] * B[0][q];
#pragma unroll
        for (int j2 = 1; j2 < D2; ++j2) t0 = fmaf(c[ii * D2 + j2], B[j2][q], t0);
        acc = fmaf(t0, A[ii][q], acc);
      }
    } else {
#pragma unroll
      for (int j2 = 0; j2 < D2; ++j2) {
        float t0 = c[j2] * A[0][q];
#pragma unroll
        for (int ii = 1; ii < D1; ++ii) t0 = fmaf(c[ii * D2 + j2], A[ii][q], t0);
        acc = fmaf(t0, B[j2][q], acc);
      }
    }
    out_lds[q * OLS + k] = acc;
  }
}

__global__ __launch_bounds__(512) void tp_kernel(
    const float* __restrict__ f1, const float* __restrict__ f2,
    const float* __restrict__ pk, const unsigned short* __restrict__ pij,
    float* __restrict__ out)
{
  __shared__ __align__(16) float f1s[NF * 4];
  __shared__ __align__(16) float f2s[NF * 4];
  __shared__ __align__(16) float out_lds[4 * OLS];
  const int z0  = (int)blockIdx.x * 4;
  const int tid = (int)threadIdx.x;
  const int wv  = tid >> 6, lane = tid & 63;

  // Stage the 4x60 feature tiles, feature-major (f[feat*4 + z]).
  if (tid < 60) {
    const f32x4 v = *(const f32x4*)(f1 + (size_t)z0 * NF + 4 * tid);
    const int g = 4 * tid, z = g / NF, f0 = g % NF;
    f1s[(f0+0)*4+z] = v[0]; f1s[(f0+1)*4+z] = v[1];
    f1s[(f0+2)*4+z] = v[2]; f1s[(f0+3)*4+z] = v[3];
  } else if (tid >= 64 && tid < 124) {
    const int t = tid - 64;
    const f32x4 v = *(const f32x4*)(f2 + (size_t)z0 * NF + 4 * t);
    const int g = 4 * t, z = g / NF, f0 = g % NF;
    f2s[(f0+0)*4+z] = v[0]; f2s[(f0+1)*4+z] = v[1];
    f2s[(f0+2)*4+z] = v[2]; f2s[(f0+3)*4+z] = v[3];
  }
  __syncthreads();

  // Balanced static schedule: 8 waves, cost 44-48 each (sum 364).
  switch (wv) {
    case 0:
      run_one<5,5>(50,pk,pij,lane,f1s,f2s,out_lds);
      run_one<3,5>(30,pk,pij,lane,f1s,f2s,out_lds);
      run_one<5,3>(43,pk,pij,lane,f1s,f2s,out_lds);
      run_one<1,5>(10,pk,pij,lane,f1s,f2s,out_lds);
      run_one<3,3>(21,pk,pij,lane,f1s,f2s,out_lds);
      run_one<1,3>( 4,pk,pij,lane,f1s,f2s,out_lds);
      run_one<3,1>(15,pk,pij,lane,f1s,f2s,out_lds); break;
    case 1:
      run_one<5,5>(51,pk,pij,lane,f1s,f2s,out_lds);
      run_one<3,5>(31,pk,pij,lane,f1s,f2s,out_lds);
      run_one<5,3>(44,pk,pij,lane,f1s,f2s,out_lds);
      run_one<1,5>(11,pk,pij,lane,f1s,f2s,out_lds);
      run_one<3,3>(22,pk,pij,lane,f1s,f2s,out_lds);
      run_one<1,3>( 5,pk,pij,lane,f1s,f2s,out_lds);
      run_one<3,1>(16,pk,pij,lane,f1s,f2s,out_lds); break;
    case 2:
      run_one<5,5>(52,pk,pij,lane,f1s,f2s,out_lds);
      run_one<3,5>(32,pk,pij,lane,f1s,f2s,out_lds);
      run_one<5,3>(45,pk,pij,lane,f1s,f2s,out_lds);
      run_one<1,5>(12,pk,pij,lane,f1s,f2s,out_lds);
      run_one<3,3>(23,pk,pij,lane,f1s,f2s,out_lds);
      run_one<1,3>( 6,pk,pij,lane,f1s,f2s,out_lds);
      run_one<3,1>(17,pk,pij,lane,f1s,f2s,out_lds); break;
    case 3:
      run_one<5,5>(53,pk,pij,lane,f1s,f2s,out_lds);
      run_one<3,5>(33,pk,pij,lane,f1s,f2s,out_lds);
      run_one<5,3>(46,pk,pij,lane,f1s,f2s,out_lds);
      run_one<1,5>(13,pk,pij,lane,f1s,f2s,out_lds);
      run_one<3,3>(24,pk,pij,lane,f1s,f2s,out_lds);
      run_one<1,3>( 7,pk,pij,lane,f1s,f2s,out_lds);
      run_one<3,1>(18,pk,pij,lane,f1s,f2s,out_lds); break;
    case 4:
      run_one<5,5>(54,pk,pij,lane,f1s,f2s,out_lds);
      run_one<3,5>(34,pk,pij,lane,f1s,f2s,out_lds);
      run_one<5,3>(47,pk,pij,lane,f1s,f2s,out_lds);
      run_one<1,5>(14,pk,pij,lane,f1s,f2s,out_lds);
      run_one<3,3>(25,pk,pij,lane,f1s,f2s,out_lds);
      run_one<1,3>( 8,pk,pij,lane,f1s,f2s,out_lds);
      run_one<1,1>( 0,pk,pij,lane,f1s,f2s,out_lds); break;
    case 5:
      run_one<5,5>(55,pk,pij,lane,f1s,f2s,out_lds);
      run_one<3,5>(36,pk,pij,lane,f1s,f2s,out_lds);
      run_one<5,3>(48,pk,pij,lane,f1s,f2s,out_lds);
      run_one<5,1>(38,pk,pij,lane,f1s,f2s,out_lds);
      run_one<3,3>(26,pk,pij,lane,f1s,f2s,out_lds);
      run_one<1,3>( 9,pk,pij,lane,f1s,f2s,out_lds);
      run_one<1,1>( 1,pk,pij,lane,f1s,f2s,out_lds); break;
    case 6:
      run_one<5,5>(56,pk,pij,lane,f1s,f2s,out_lds);
      run_one<3,5>(35,pk,pij,lane,f1s,f2s,out_lds);
      run_one<5,3>(49,pk,pij,lane,f1s,f2s,out_lds);
      run_one<5,1>(39,pk,pij,lane,f1s,f2s,out_lds);
      run_one<3,3>(27,pk,pij,lane,f1s,f2s,out_lds);
      run_one<3,1>(19,pk,pij,lane,f1s,f2s,out_lds);
      run_one<1,1>( 2,pk,pij,lane,f1s,f2s,out_lds); break;
    default:
      run_one<5,5>(37,pk,pij,lane,f1s,f2s,out_lds);
      run_one<5,3>(42,pk,pij,lane,f1s,f2s,out_lds);
      run_one<5,1>(40,pk,pij,lane,f1s,f2s,out_lds);
      run_one<5,1>(41,pk,pij,lane,f1s,f2s,out_lds);
      run_one<3,3>(28,pk,pij,lane,f1s,f2s,out_lds);
      run_one<3,3>(29,pk,pij,lane,f1s,f2s,out_lds);
      run_one<3,1>(20,pk,pij,lane,f1s,f2s,out_lds);
      run_one<1,1>( 3,pk,pij,lane,f1s,f2s,out_lds); break;
  }
  __syncthreads();

  // Sweep: ONE contiguous 57.6KB slab per block, fully coalesced f32x4.
  float* ob = out + (size_t)z0 * KTOT;
#pragma unroll 1
  for (int t = tid; t < KTOT; t += 512) {          // 3600 f32x4 records
    const int z = t / 900, kq = t - z * 900;
    *(f32x4*)(ob + (size_t)z * KTOT + 4 * kq) =
        *(const f32x4*)&out_lds[z * OLS + 4 * kq];
  }
}

extern "C" void kernel_launch(void* const* d_in, const int* in_sizes, int n_in,
                              void* d_out, int out_size, void* d_ws, size_t ws_size,
                              hipStream_t stream) {
  const float* f1 = (const float*)d_in[0];
  const float* f2 = (const float*)d_in[1];
  const float* M  = (const float*)d_in[2];
  float* out = (float*)d_out;
  float* pk  = (float*)d_ws;                                      // 181,248 B
  unsigned short* pij = (unsigned short*)((char*)d_ws + PIJ_OFF); //   7,296 B

  pack_kernel<<<dim3((3648 * 8) / 256), dim3(256), 0, stream>>>(M, pk, pij);

  const int Z = in_sizes[0] / NF;          // 4096
  tp_kernel<<<dim3(Z / 4), dim3(512), 0, stream>>>(f1, f2, pk, pij, out);
}